// Round 19
// baseline (729.967 us; speedup 1.0000x reference)
//
#include <hip/hip_runtime.h>
#include <stdint.h>

#define B_DIM 512
#define I_DIM 128
#define H_DIM 128
#define G_DIM 384
#define NSTEP 511   // reference scans t = 0..T-2

typedef __attribute__((ext_vector_type(8))) short bf16x8;
typedef __attribute__((ext_vector_type(4))) float f32x4;
typedef _Float16 half2_t __attribute__((ext_vector_type(2)));
typedef _Float16 half8_t __attribute__((ext_vector_type(8)));

// Barrier draining ONLY LDS ops; global prefetches stay in flight across it.
#define BAR_LDS() asm volatile("s_waitcnt lgkmcnt(0)\n\ts_barrier" ::: "memory")
#define MFMA16(A, B, C) __builtin_amdgcn_mfma_f32_16x16x32_f16(A, B, C, 0, 0, 0)

__device__ __forceinline__ unsigned bf16rne(float f) {
  unsigned u = __float_as_uint(f);
  return (u + 0x7fffu + ((u >> 16) & 1u)) >> 16;
}
__device__ __forceinline__ short bf16s(float f) { return (short)bf16rne(f); }
__device__ __forceinline__ float frcp(float v) {
#if __has_builtin(__builtin_amdgcn_rcpf)
  return __builtin_amdgcn_rcpf(v);
#else
  return 1.f / v;
#endif
}
__device__ __forceinline__ unsigned pkrtz_u(float a, float b) {
#if __has_builtin(__builtin_amdgcn_cvt_pkrtz)
  return __builtin_bit_cast(unsigned, __builtin_amdgcn_cvt_pkrtz(a, b));
#else
  half2_t r; r.x = (_Float16)a; r.y = (_Float16)b;
  return __builtin_bit_cast(unsigned, r);
#endif
}
__device__ __forceinline__ f32x4 unpack_u2(uint2 v) {
  const half2_t a = __builtin_bit_cast(half2_t, v.x);
  const half2_t b = __builtin_bit_cast(half2_t, v.y);
  return (f32x4){(float)a.x, (float)a.y, (float)b.x, (float)b.y};
}

// ---------------------------------------------------------------------------
// Kernel A (full-chip MFMA GEMM, r6-verified core): xp[t][g][b] (TRANSPOSED,
// f16) = x[t,b,:].Wih[g,:] + bih[g] (+bhh[g] for the r,z thirds). One block =
// one 128-row tile (4 tiles per step). Transposed layout makes the rec-side
// C-init a single b64 load per gate (4 consecutive b = D-fragment rows).
// ---------------------------------------------------------------------------
__global__ __launch_bounds__(512, 2) void k_xproj(
    const float* __restrict__ xch, const float* __restrict__ Wih,
    const float* __restrict__ bih, const float* __restrict__ bhh,
    _Float16* __restrict__ xp) {
  __shared__ __align__(16) char As[128 * 256];  // 32 KB bf16 A tile
  const int tid = threadIdx.x;
  const int lane = tid & 63;
  const int wave = tid >> 6;
  const int mh = wave & 1, nh = wave >> 1;
  const int l15 = lane & 15, l4 = lane >> 4;

  const float4* xs = (const float4*)(xch + (size_t)blockIdx.x * 128 * I_DIM);
#pragma unroll
  for (int q = 0; q < 8; ++q) {
    const int fi = tid + 512 * q;
    const int row = fi >> 5, kq = fi & 31;
    const float4 v = xs[fi];
    uint2 p;
    p.x = bf16rne(v.x) | (bf16rne(v.y) << 16);
    p.y = bf16rne(v.z) | (bf16rne(v.w) << 16);
    *(uint2*)(As + (row << 8) + ((kq << 3) ^ ((row & 7) << 4))) = p;
  }

  bf16x8 bf[6][4];
  float bv[6];
#pragma unroll
  for (int nf = 0; nf < 6; ++nf) {
    const int col = nh * 96 + nf * 16 + l15;
    bv[nf] = bih[col] + (col < 256 ? bhh[col] : 0.f);  // fold bhh for r,z
#pragma unroll
    for (int ks = 0; ks < 4; ++ks) {
      const float* wr = Wih + (size_t)col * I_DIM + ks * 32 + l4 * 8;
      const float4 wa = *(const float4*)wr;
      const float4 wb = *(const float4*)(wr + 4);
      bf16x8 b;
      b[0] = bf16s(wa.x); b[1] = bf16s(wa.y); b[2] = bf16s(wa.z); b[3] = bf16s(wa.w);
      b[4] = bf16s(wb.x); b[5] = bf16s(wb.y); b[6] = bf16s(wb.z); b[7] = bf16s(wb.w);
      bf[nf][ks] = b;
    }
  }
  __syncthreads();

  f32x4 acc[4][6];
#pragma unroll
  for (int m = 0; m < 4; ++m)
#pragma unroll
    for (int nf = 0; nf < 6; ++nf) acc[m][nf] = (f32x4){0.f, 0.f, 0.f, 0.f};

#pragma unroll
  for (int ks = 0; ks < 4; ++ks) {
#pragma unroll
    for (int m = 0; m < 4; ++m) {
      const int arow = mh * 64 + m * 16 + l15;
      const int kbyte = ks * 64 + l4 * 16;
      const bf16x8 a =
          *(const bf16x8*)(As + (arow << 8) + (kbyte ^ ((arow & 7) << 4)));
#pragma unroll
      for (int nf = 0; nf < 6; ++nf)
        acc[m][nf] = __builtin_amdgcn_mfma_f32_16x16x32_bf16(
            a, bf[nf][ks], acc[m][nf], 0, 0, 0);
    }
  }

  // epilogue: TRANSPOSED b64 writes — xp[trel][col][b0..b0+3]
  const int trel = blockIdx.x >> 2;   // chunk-local step
#pragma unroll
  for (int m = 0; m < 4; ++m) {
    const int b0 = (blockIdx.x & 3) * 128 + mh * 64 + m * 16 + l4 * 4;
#pragma unroll
    for (int nf = 0; nf < 6; ++nf) {
      const int col = nh * 96 + nf * 16 + l15;
      uint2 p;
      p.x = pkrtz_u(acc[m][nf][0] + bv[nf], acc[m][nf][1] + bv[nf]);
      p.y = pkrtz_u(acc[m][nf][2] + bv[nf], acc[m][nf][3] + bv[nf]);
      *(uint2*)&xp[((size_t)trel * G_DIM + col) * B_DIM + b0] = p;
    }
  }
}

// ---------------------------------------------------------------------------
// Kernel B: h-ONLY recurrence. 32 blocks x 16 rows, 512 threads = 8 waves
// (2/SIMD). Per step: 4 ds_read_b128 (h A-frags) + 3 global b64 xp loads
// (transposed layout -> exact C-init fragments; prefetched 1 step ahead,
// fly over the lgkm-only barrier) + 12 MFMA + lane-local gate math +
// 4 ds_write_b16 + ONE barrier. No x-role, no pp exchange. Decode+NLL via
// 4 MFMAs on wave 0. Chunked over t if ws can't hold all 201 MB of xp.
// ---------------------------------------------------------------------------
__global__ __launch_bounds__(512, 1) void k_rec(
    const _Float16* __restrict__ xp, const float* __restrict__ gt,
    const float* __restrict__ Whh, const float* __restrict__ bhh,
    const float* __restrict__ Wdec, const float* __restrict__ bdec,
    float* __restrict__ ws_h, float* __restrict__ nll_part,
    int t0, int t1, int first) {
  __shared__ __align__(16) _Float16 hT[2][16 * 128];  // 8 KB, dbuf h tiles
  __shared__ float gl[NSTEP * 16];                    // 32.7 KB gt slice

  const int tid = threadIdx.x;
  const int lane = tid & 63;
  const int w = tid >> 6;
  const int l15 = lane & 15, l4 = lane >> 4;
  const int row0 = blockIdx.x * 16;
  const int u = 16 * w + l15;
  const int nT = t1 - t0;

  // ---- gt preload for this chunk: gl[s*16+c] = gt[s+1][row0+c] ----
#pragma unroll
  for (int q = 0; q < 16; ++q) {
    const int k = tid + 512 * q;
    const int idx = t0 * 16 + k;
    if (idx < t1 * 16)
      gl[idx] = gt[(size_t)((idx >> 4) + 1) * B_DIM + row0 + (idx & 15)];
  }

  // ---- one-time: Whh B-frags + decode frag ----
  half8_t bh[3][4];
#pragma unroll
  for (int g3 = 0; g3 < 3; ++g3)
#pragma unroll
    for (int ks = 0; ks < 4; ++ks) {
      const size_t off = (size_t)(g3 * H_DIM + u) * H_DIM + ks * 32 + l4 * 8;
      const float4 a = *(const float4*)(Whh + off);
      const float4 b = *(const float4*)(Whh + off + 4);
      half8_t v;
      v[0] = (_Float16)a.x; v[1] = (_Float16)a.y;
      v[2] = (_Float16)a.z; v[3] = (_Float16)a.w;
      v[4] = (_Float16)b.x; v[5] = (_Float16)b.y;
      v[6] = (_Float16)b.z; v[7] = (_Float16)b.w;
      bh[g3][ks] = v;
    }
  half8_t wdB[4];
#pragma unroll
  for (int ks = 0; ks < 4; ++ks) {
    half8_t v;
#pragma unroll
    for (int j = 0; j < 8; ++j)
      v[j] = (l15 == 0) ? (_Float16)Wdec[ks * 32 + l4 * 8 + j] : (_Float16)0.f;
    wdB[ks] = v;
  }
  const float bhn = bhh[2 * H_DIM + u];
  const float bd0 = bdec[0];
  const f32x4 cN = (f32x4){bhn, bhn, bhn, bhn};

  // ---- init h (regs + swizzled tile 0) ----
  float h_old[4];
#pragma unroll
  for (int r = 0; r < 4; ++r) {
    const int b = 4 * l4 + r;
    h_old[r] = first ? 0.f : ws_h[(size_t)(row0 + b) * H_DIM + u];
    *(_Float16*)((char*)hT[0] + b * 256 + (((u >> 3) ^ b) << 4) + (u & 7) * 2) =
        (_Float16)h_old[r];
  }

  // ---- xp prefetch for lt=0 (transposed: one b64 per gate) ----
  const int b0i = row0 + 4 * l4;
  uint2 xqR = *(const uint2*)&xp[((size_t)0 * G_DIM + u) * B_DIM + b0i];
  uint2 xqZ = *(const uint2*)&xp[((size_t)0 * G_DIM + H_DIM + u) * B_DIM + b0i];
  uint2 xqN = *(const uint2*)&xp[((size_t)0 * G_DIM + 2 * H_DIM + u) * B_DIM + b0i];

  float nllA[4] = {0.f, 0.f, 0.f, 0.f};
  __syncthreads();

#pragma unroll 1
  for (int s = t0; s < t1; ++s) {
    const int lt = s - t0;
    // A-fragments for h(s)
    const char* hb = (const char*)hT[lt & 1];
    half8_t ah[4];
#pragma unroll
    for (int ks = 0; ks < 4; ++ks)
      ah[ks] = *(const half8_t*)(hb + l15 * 256 +
                                 ((((ks << 2) | l4) ^ l15) << 4));

    // C-init from prefetched xp (biases for r,z folded upstream)
    f32x4 aR = unpack_u2(xqR);
    f32x4 aZ = unpack_u2(xqZ);
    const f32x4 pN = unpack_u2(xqN);
    f32x4 aN = cN;
#pragma unroll
    for (int ks = 0; ks < 4; ++ks) {
      aR = MFMA16(ah[ks], bh[0][ks], aR);
      aZ = MFMA16(ah[ks], bh[1][ks], aZ);
      aN = MFMA16(ah[ks], bh[2][ks], aN);
    }

    // issue next step's xp loads (consumed next iter; fly over the barrier)
    {
      const size_t nlt = (size_t)((lt + 1 < nT) ? lt + 1 : lt);
      xqR = *(const uint2*)&xp[(nlt * G_DIM + u) * B_DIM + b0i];
      xqZ = *(const uint2*)&xp[(nlt * G_DIM + H_DIM + u) * B_DIM + b0i];
      xqN = *(const uint2*)&xp[(nlt * G_DIM + 2 * H_DIM + u) * B_DIM + b0i];
    }

    // decode + NLL for h(s) vs gt[s] (wave 0; chunk-start handled upstream)
    if (w == 0 && s > t0) {
      f32x4 aD = (f32x4){0.f, 0.f, 0.f, 0.f};
#pragma unroll
      for (int ks = 0; ks < 4; ++ks) aD = MFMA16(ah[ks], wdB[ks], aD);
      if (l15 == 0) {
#pragma unroll
        for (int r = 0; r < 4; ++r) {
          const float C = frcp(1.f + __expf(-(aD[r] + bd0)));
          const float g = gl[(s - 1) * 16 + 4 * l4 + r];
          nllA[r] -= g * __logf(C + 1e-4f) +
                     (1.f - g) * __logf(1.f - C + 1e-4f);
        }
      }
    }

    // lean gate math; write hnew f16 into the other h tile
    char* hw = (char*)hT[(lt + 1) & 1];
#pragma unroll
    for (int r = 0; r < 4; ++r) {
      const float r_ = frcp(1.f + __expf(-aR[r]));
      const float z_ = frcp(1.f + __expf(-aZ[r]));
      const float a2 = pN[r] + r_ * aN[r];
      const float n_ = 1.f - 2.f * frcp(__expf(2.f * a2) + 1.f);
      const float hnew = n_ + z_ * (h_old[r] - n_);
      h_old[r] = hnew;
      const int b = 4 * l4 + r;
      *(_Float16*)(hw + b * 256 + (((u >> 3) ^ b) << 4) + (u & 7) * 2) =
          (_Float16)hnew;
    }
    BAR_LDS();  // the ONE barrier: h(s+1) published
  }

  // ---- epilogue: decode h(t1) vs gt[t1]; persist state ----
  if (w == 0) {
    const char* hb = (const char*)hT[nT & 1];
    half8_t ah[4];
#pragma unroll
    for (int ks = 0; ks < 4; ++ks)
      ah[ks] = *(const half8_t*)(hb + l15 * 256 +
                                 ((((ks << 2) | l4) ^ l15) << 4));
    f32x4 aD = (f32x4){0.f, 0.f, 0.f, 0.f};
#pragma unroll
    for (int ks = 0; ks < 4; ++ks) aD = MFMA16(ah[ks], wdB[ks], aD);
    if (l15 == 0) {
#pragma unroll
      for (int r = 0; r < 4; ++r) {
        const float C = frcp(1.f + __expf(-(aD[r] + bd0)));
        const float g = gl[(t1 - 1) * 16 + 4 * l4 + r];
        nllA[r] -= g * __logf(C + 1e-4f) +
                   (1.f - g) * __logf(1.f - C + 1e-4f);
        const int rr = row0 + 4 * l4 + r;
        nll_part[rr] = first ? nllA[r] : (nll_part[rr] + nllA[r]);
      }
    }
  }
#pragma unroll
  for (int r = 0; r < 4; ++r)
    ws_h[(size_t)(row0 + 4 * l4 + r) * H_DIM + u] = h_old[r];
}

// ---------------------------------------------------------------------------
__global__ __launch_bounds__(512) void k_fin(const float* __restrict__ nll_part,
                                             float* __restrict__ out) {
  __shared__ float red[8];
  const int tid = threadIdx.x;
  float v = nll_part[tid];
#pragma unroll
  for (int off = 32; off; off >>= 1) v += __shfl_down(v, off);
  if ((tid & 63) == 0) red[tid >> 6] = v;
  __syncthreads();
  if (tid == 0) {
    float s = 0.f;
#pragma unroll
    for (int i = 0; i < 8; ++i) s += red[i];
    out[0] = s * (1.f / (512.f * 512.f));
  }
}

// ---------------------------------------------------------------------------
extern "C" void kernel_launch(void* const* d_in, const int* in_sizes, int n_in,
                              void* d_out, int out_size, void* d_ws,
                              size_t ws_size, hipStream_t stream) {
  const float* x    = (const float*)d_in[0];
  const float* gt   = (const float*)d_in[1];
  const float* Wih  = (const float*)d_in[2];
  const float* Whh  = (const float*)d_in[3];
  const float* bih  = (const float*)d_in[4];
  const float* bhh  = (const float*)d_in[5];
  const float* Wdec = (const float*)d_in[6];
  const float* bdec = (const float*)d_in[7];

  // ws: [0,2KB) nll_part; [4KB,260KB) h state; then xp chunk (f16, [t][g][b])
  float* nll_part = (float*)d_ws;
  float* ws_h = (float*)((char*)d_ws + 4096);
  const size_t xp_off = 4096 + (size_t)B_DIM * H_DIM * 4;   // 266240
  _Float16* xp = (_Float16*)((char*)d_ws + xp_off);

  const size_t per_step = (size_t)G_DIM * B_DIM * 2;        // 384 KB f16
  size_t avail = ws_size > xp_off ? ws_size - xp_off : 0;
  int Tc = (int)(avail / per_step);
  if (Tc > NSTEP) Tc = NSTEP;
  if (Tc < 1) Tc = 1;

  for (int t0 = 0; t0 < NSTEP; t0 += Tc) {
    int t1 = t0 + Tc;
    if (t1 > NSTEP) t1 = NSTEP;
    const int nt = t1 - t0;
    k_xproj<<<dim3(nt * 4), dim3(512), 0, stream>>>(
        x + (size_t)t0 * B_DIM * I_DIM, Wih, bih, bhh, xp);
    k_rec<<<dim3(32), dim3(512), 0, stream>>>(
        xp, gt, Whh, bhh, Wdec, bdec, ws_h, nll_part, t0, t1, t0 == 0 ? 1 : 0);
  }
  k_fin<<<dim3(1), dim3(512), 0, stream>>>(nll_part, (float*)d_out);
}